// Round 16
// baseline (116.408 us; speedup 1.0000x reference)
//
#include <hip/hip_runtime.h>
#include <math.h>

// Closed form derived from the reference:
//   q[n,0] = prod_{v=1..7} cos(x[n,v]+theta[v])
//   q[n,w] = prod_{v=0..w} cos(x[n,v]+theta[v])   (w = 1..7)
// Attention with E=8, no-max softmax (|score| <= 8/sqrt2), output scramble:
//   final[b,r,k] = sum_c att[b,(r%512)*8+c, r/512] * W[k,c] + bias[k].
//
// R15: R13 (best: 32x32x16 + permuted-k, SROWS=128, grid 512) + ILP:
//      dual PV accumulators o0/o1 break the 32-deep serial MFMA-accumulate
//      chain into two 16-deep chains (tile's two PVs become independent),
//      unroll 4 lets next tile's ds_reads/QK issue under current exp2s.
//      (R14 post-mortem: halving SROWS doubled redundant staging — reverted.)

#define SEQ   4096
#define NB    16
#define SROWS 128          // s-rows per block (4 subtiles x 32)
#define TPB   1024
#define NTG   4            // t-groups
#define TC    1024         // t rows staged per chunk
#define NCH   (SEQ / TC)   // 4 chunks
#define TILES_PER_TG 8     // (TC/32)/NTG
#define KSTR  12           // kf row stride in f16 (24 B)
#define VSTR  1028         // vt row stride in f16 (bank-offset 2 per row)

typedef _Float16 f16x4  __attribute__((ext_vector_type(4)));
typedef _Float16 f16x8  __attribute__((ext_vector_type(8)));
typedef float    f32x16 __attribute__((ext_vector_type(16)));
typedef __fp16   hf2    __attribute__((ext_vector_type(2)));

#if __has_builtin(__builtin_amdgcn_exp2f)
#define EXP2F(x) __builtin_amdgcn_exp2f(x)
#else
#define EXP2F(x) exp2f(x)
#endif

__global__ __launch_bounds__(TPB, 8)   // VGPR cap 64; 2 blocks/CU -> 32 waves/CU
void qattn_kernel(const float* __restrict__ x, const float* __restrict__ theta,
                  const float* __restrict__ wc, const float* __restrict__ bc,
                  float* __restrict__ out)
{
    __shared__ __align__(16) _Float16 kf[TC * KSTR];  // 24576 B: [t][8 f16 + 4 pad]
    __shared__ __align__(16) _Float16 vt[9 * VSTR];   // 18504 B: [w][t], w=8 = ones
    // after the last MFMA barrier these are re-used:
    float* part = (float*)kf;            // [NTG][SROWS][9] = 18432 B
    float* attn = (float*)vt;            // [SROWS][9]      =  4608 B

    const int tid  = threadIdx.x;
    const int lane = tid & 63;
    const int wv   = tid >> 6;           // 0..15
    const int sub  = wv & 3;             // s-subtile (32 rows)
    const int tg   = wv >> 2;            // t-group
    const int l31  = lane & 31;
    const int hp   = lane >> 5;

    const int b  = blockIdx.x >> 5;
    const int S0 = (blockIdx.x & 31) * SROWS;
    const float* xb = x + (size_t)b * SEQ * 8;

    float th[8];
#pragma unroll
    for (int w = 0; w < 8; ++w) th[w] = theta[w];

    // ones (denominator) row: constant across chunks, write once.
    vt[8 * VSTR + tid] = (_Float16)1.0f;

    // ---- Q fragment (B of QK, 32x32x16): B[k=8hp+j][n=s=l31]; hp1 = zeros ----
    f16x8 qfrag = {(_Float16)0.f, (_Float16)0.f, (_Float16)0.f, (_Float16)0.f,
                   (_Float16)0.f, (_Float16)0.f, (_Float16)0.f, (_Float16)0.f};
    {
        const int s = S0 + sub * 32 + l31;
        const float4 xa  = *(const float4*)(xb + s * 8);
        const float4 xb4 = *(const float4*)(xb + s * 8 + 4);
        float c0 = __cosf(xa.x  + th[0]);
        float c1 = __cosf(xa.y  + th[1]);
        float c2 = __cosf(xa.z  + th[2]);
        float c3 = __cosf(xa.w  + th[3]);
        float c4 = __cosf(xb4.x + th[4]);
        float c5 = __cosf(xb4.y + th[5]);
        float c6 = __cosf(xb4.z + th[6]);
        float c7 = __cosf(xb4.w + th[7]);
        float p1 = c0 * c1, p2 = p1 * c2, p3 = p2 * c3, p4 = p3 * c4;
        float p5 = p4 * c5, p6 = p5 * c6, p7 = p6 * c7;
        float p0 = c1 * c2 * c3 * c4 * c5 * c6 * c7;
        const float sc = 0.70710678118654752f * 1.44269504088896341f;
        if (hp == 0)
            qfrag = (f16x8){(_Float16)(p0*sc), (_Float16)(p1*sc),
                            (_Float16)(p2*sc), (_Float16)(p3*sc),
                            (_Float16)(p4*sc), (_Float16)(p5*sc),
                            (_Float16)(p6*sc), (_Float16)(p7*sc)};
    }

    const f32x16 Z = {0.f,0.f,0.f,0.f,0.f,0.f,0.f,0.f,
                      0.f,0.f,0.f,0.f,0.f,0.f,0.f,0.f};
    f32x16 o0 = Z, o1 = Z;               // dual PV accumulators (independent chains)

    const int wr = (l31 < 8) ? l31 : 8;  // lanes w>=8 broadcast-read ones row
    // QK A (kf): both half-waves read k=0..7 (hp1's k=8..15 multiply B=0)
    const _Float16* kfb = kf + l31 * KSTR + (tg * TILES_PER_TG) * 32 * KSTR;
    // PV B (vt): permuted-k scramble = +4*hp, immediates 0/8/16/24
    const _Float16* vbb = vt + wr * VSTR + 4 * hp + tg * (TILES_PER_TG * 32);

    for (int ch = 0; ch < NCH; ++ch) {
        __syncthreads();                  // previous chunk's readers done
        // ---- stage TC t-rows (1 per thread): kf wires + padded vt ----
        {
            const int t = ch * TC + tid;
            const float4 xa  = *(const float4*)(xb + t * 8);
            const float4 xb4 = *(const float4*)(xb + t * 8 + 4);
            float c0 = __cosf(xa.x  + th[0]);
            float c1 = __cosf(xa.y  + th[1]);
            float c2 = __cosf(xa.z  + th[2]);
            float c3 = __cosf(xa.w  + th[3]);
            float c4 = __cosf(xb4.x + th[4]);
            float c5 = __cosf(xb4.y + th[5]);
            float c6 = __cosf(xb4.z + th[6]);
            float c7 = __cosf(xb4.w + th[7]);
            float p1 = c0 * c1, p2 = p1 * c2, p3 = p2 * c3, p4 = p3 * c4;
            float p5 = p4 * c5, p6 = p5 * c6, p7 = p6 * c7;
            float p0 = c1 * c2 * c3 * c4 * c5 * c6 * c7;
            _Float16 h0 = (_Float16)p0, h1 = (_Float16)p1, h2 = (_Float16)p2,
                     h3 = (_Float16)p3, h4 = (_Float16)p4, h5 = (_Float16)p5,
                     h6 = (_Float16)p6, h7 = (_Float16)p7;
            _Float16* krow = kf + tid * KSTR;
            *(f16x4*)(krow)     = (f16x4){h0, h1, h2, h3};
            *(f16x4*)(krow + 4) = (f16x4){h4, h5, h6, h7};
            vt[0 * VSTR + tid] = h0;
            vt[1 * VSTR + tid] = h1;
            vt[2 * VSTR + tid] = h2;
            vt[3 * VSTR + tid] = h3;
            vt[4 * VSTR + tid] = h4;
            vt[5 * VSTR + tid] = h5;
            vt[6 * VSTR + tid] = h6;
            vt[7 * VSTR + tid] = h7;
        }
        __syncthreads();
        // ---- 8 t-tiles: QK(K=16) -> exp2/pkrtz -> 2 PV(K=16, permuted k) ----
#pragma unroll 4
        for (int i = 0; i < TILES_PER_TG; ++i) {
            const _Float16* kp = kfb + i * 32 * KSTR;
            union { f16x4 h[2]; f16x8 v; } kfr;
            kfr.h[0] = *(const f16x4*)(kp);
            kfr.h[1] = *(const f16x4*)(kp + 4);
            f32x16 cc = __builtin_amdgcn_mfma_f32_32x32x16_f16(kfr.v, qfrag, Z, 0, 0, 0);
            // P stays in C-reg order; A-frags = C-regs 0..7 and 8..15 verbatim
            union { int i_[4]; f16x8 v; } A0, A1;
#pragma unroll
            for (int j = 0; j < 4; ++j) {
                union { hf2 h; int i_; } t2;
                t2.h = __builtin_amdgcn_cvt_pkrtz(EXP2F(cc[2*j]), EXP2F(cc[2*j+1]));
                A0.i_[j] = t2.i_;
            }
            const _Float16* vp = vbb + i * 32;
            union { f16x4 h[2]; f16x8 v; } vf0, vf1;
            vf0.h[0] = *(const f16x4*)(vp);
            vf0.h[1] = *(const f16x4*)(vp + 8);
            o0 = __builtin_amdgcn_mfma_f32_32x32x16_f16(A0.v, vf0.v, o0, 0, 0, 0);
#pragma unroll
            for (int j = 0; j < 4; ++j) {
                union { hf2 h; int i_; } t2;
                t2.h = __builtin_amdgcn_cvt_pkrtz(EXP2F(cc[8+2*j]), EXP2F(cc[8+2*j+1]));
                A1.i_[j] = t2.i_;
            }
            vf1.h[0] = *(const f16x4*)(vp + 16);
            vf1.h[1] = *(const f16x4*)(vp + 24);
            o1 = __builtin_amdgcn_mfma_f32_32x32x16_f16(A1.v, vf1.v, o1, 0, 0, 0);
        }
    }

    // merge the two accumulator chains
    f32x16 o = o0 + o1;

    // ---- write per-t-group partials (cols 0..8; col 8 = exp-sum) ----
    __syncthreads();                      // all MFMA reads of kf/vt done; alias now
    if (l31 < 9) {
#pragma unroll
        for (int r = 0; r < 16; ++r) {
            const int sloc = sub * 32 + (r & 3) + 8 * (r >> 2) + 4 * hp;
            part[((tg * SROWS) + sloc) * 9 + l31] = o[r];
        }
    }
    __syncthreads();
    // ---- reduce over t-groups (1152 entries > TPB: strided loop!) ----
    for (int idx = tid; idx < SROWS * 9; idx += TPB) {
        const int rr = idx / 9;
        const int w  = idx - rr * 9;
        float sm = 0.f;
#pragma unroll
        for (int g = 0; g < NTG; ++g) sm += part[((g * SROWS) + rr) * 9 + w];
        attn[rr * 9 + w] = sm;
    }
    __syncthreads();
    if (tid < SROWS * 8) {                // normalize in place (col 8 untouched)
        const int rr = tid >> 3;
        const int w  = tid & 7;
        attn[rr * 9 + w] = attn[rr * 9 + w] / attn[rr * 9 + 8];
    }
    __syncthreads();

    // ---- epilogue: swapaxes/reshape scramble + 8x8 combine ----
    if (tid < SROWS) {
        const int e    = tid >> 4;        // wire
        const int nloc = tid & 15;
        const int r    = e * 512 + (S0 >> 3) + nloc;
        float y[8];
#pragma unroll
        for (int c = 0; c < 8; ++c) y[c] = attn[(nloc * 8 + c) * 9 + e];
        float oo[8];
#pragma unroll
        for (int k = 0; k < 8; ++k) {
            float a = bc[k];
#pragma unroll
            for (int c = 0; c < 8; ++c) a += y[c] * wc[k * 8 + c];
            oo[k] = a;
        }
        float4* op = (float4*)(out + ((size_t)b * SEQ + r) * 8);
        op[0] = make_float4(oo[0], oo[1], oo[2], oo[3]);
        op[1] = make_float4(oo[4], oo[5], oo[6], oo[7]);
    }
}

extern "C" void kernel_launch(void* const* d_in, const int* in_sizes, int n_in,
                              void* d_out, int out_size, void* d_ws, size_t ws_size,
                              hipStream_t stream)
{
    const float* x  = (const float*)d_in[0];
    const float* th = (const float*)d_in[1];
    const float* wc = (const float*)d_in[2];
    const float* bc = (const float*)d_in[3];
    float* out = (float*)d_out;

    qattn_kernel<<<dim3(NB * (SEQ / SROWS)), dim3(TPB), 0, stream>>>(x, th, wc, bc, out);
}

// Round 17
// 91.019 us; speedup vs baseline: 1.2789x; 1.2789x over previous
//
#include <hip/hip_runtime.h>
#include <math.h>

// Closed form derived from the reference:
//   q[n,0] = prod_{v=1..7} cos(x[n,v]+theta[v])
//   q[n,w] = prod_{v=0..w} cos(x[n,v]+theta[v])   (w = 1..7)
// Attention with E=8, no-max softmax (|score| <= 8/sqrt2), output scramble:
//   final[b,r,k] = sum_c att[b,(r%512)*8+c, r/512] * W[k,c] + bias[k].
//
// R16 = R13 revert (best verified: profiled ~40us). R15's dual accumulators +
//      unroll 4 spilled to scratch (WRITE_SIZE 2->150 MB) under the 64-VGPR
//      cap. R13 structure: 32x32x16 MFMA with permuted-k PV (P stays in QK's
//      C-reg order; V^T read through the same k-scramble -> C-regs 0..7/8..15
//      ARE the PV A-frags, no cross-lane ops), Q zeroed on hp1 so kf needs no
//      K-padding, TPB=1024 = 4 s-subtiles x 4 t-groups, 2 blocks/CU.

#define SEQ   4096
#define NB    16
#define SROWS 128          // s-rows per block (4 subtiles x 32)
#define TPB   1024
#define NTG   4            // t-groups
#define TC    1024         // t rows staged per chunk
#define NCH   (SEQ / TC)   // 4 chunks
#define TILES_PER_TG 8     // (TC/32)/NTG
#define KSTR  12           // kf row stride in f16 (24 B)
#define VSTR  1028         // vt row stride in f16 (bank-offset 2 per row)

typedef _Float16 f16x4  __attribute__((ext_vector_type(4)));
typedef _Float16 f16x8  __attribute__((ext_vector_type(8)));
typedef float    f32x16 __attribute__((ext_vector_type(16)));
typedef __fp16   hf2    __attribute__((ext_vector_type(2)));

#if __has_builtin(__builtin_amdgcn_exp2f)
#define EXP2F(x) __builtin_amdgcn_exp2f(x)
#else
#define EXP2F(x) exp2f(x)
#endif

__global__ __launch_bounds__(TPB, 8)   // VGPR cap 64; 2 blocks/CU -> 32 waves/CU
void qattn_kernel(const float* __restrict__ x, const float* __restrict__ theta,
                  const float* __restrict__ wc, const float* __restrict__ bc,
                  float* __restrict__ out)
{
    __shared__ __align__(16) _Float16 kf[TC * KSTR];  // 24576 B: [t][8 f16 + 4 pad]
    __shared__ __align__(16) _Float16 vt[9 * VSTR];   // 18504 B: [w][t], w=8 = ones
    // after the last MFMA barrier these are re-used:
    float* part = (float*)kf;            // [NTG][SROWS][9] = 18432 B
    float* attn = (float*)vt;            // [SROWS][9]      =  4608 B

    const int tid  = threadIdx.x;
    const int lane = tid & 63;
    const int wv   = tid >> 6;           // 0..15
    const int sub  = wv & 3;             // s-subtile (32 rows)
    const int tg   = wv >> 2;            // t-group
    const int l31  = lane & 31;
    const int hp   = lane >> 5;

    const int b  = blockIdx.x >> 5;
    const int S0 = (blockIdx.x & 31) * SROWS;
    const float* xb = x + (size_t)b * SEQ * 8;

    float th[8];
#pragma unroll
    for (int w = 0; w < 8; ++w) th[w] = theta[w];

    // ones (denominator) row: constant across chunks, write once.
    vt[8 * VSTR + tid] = (_Float16)1.0f;

    // ---- Q fragment (B of QK, 32x32x16): B[k=8hp+j][n=s=l31]; hp1 = zeros ----
    f16x8 qfrag = {(_Float16)0.f, (_Float16)0.f, (_Float16)0.f, (_Float16)0.f,
                   (_Float16)0.f, (_Float16)0.f, (_Float16)0.f, (_Float16)0.f};
    {
        const int s = S0 + sub * 32 + l31;
        const float4 xa  = *(const float4*)(xb + s * 8);
        const float4 xb4 = *(const float4*)(xb + s * 8 + 4);
        float c0 = __cosf(xa.x  + th[0]);
        float c1 = __cosf(xa.y  + th[1]);
        float c2 = __cosf(xa.z  + th[2]);
        float c3 = __cosf(xa.w  + th[3]);
        float c4 = __cosf(xb4.x + th[4]);
        float c5 = __cosf(xb4.y + th[5]);
        float c6 = __cosf(xb4.z + th[6]);
        float c7 = __cosf(xb4.w + th[7]);
        float p1 = c0 * c1, p2 = p1 * c2, p3 = p2 * c3, p4 = p3 * c4;
        float p5 = p4 * c5, p6 = p5 * c6, p7 = p6 * c7;
        float p0 = c1 * c2 * c3 * c4 * c5 * c6 * c7;
        const float sc = 0.70710678118654752f * 1.44269504088896341f;
        if (hp == 0)
            qfrag = (f16x8){(_Float16)(p0*sc), (_Float16)(p1*sc),
                            (_Float16)(p2*sc), (_Float16)(p3*sc),
                            (_Float16)(p4*sc), (_Float16)(p5*sc),
                            (_Float16)(p6*sc), (_Float16)(p7*sc)};
    }

    const f32x16 Z = {0.f,0.f,0.f,0.f,0.f,0.f,0.f,0.f,
                      0.f,0.f,0.f,0.f,0.f,0.f,0.f,0.f};
    f32x16 o = Z;

    const int wr = (l31 < 8) ? l31 : 8;  // lanes w>=8 broadcast-read ones row
    // QK A (kf): both half-waves read k=0..7 (hp1's k=8..15 multiply B=0)
    const _Float16* kfb = kf + l31 * KSTR + (tg * TILES_PER_TG) * 32 * KSTR;
    // PV B (vt): permuted-k scramble = +4*hp, immediates 0/8/16/24
    const _Float16* vbb = vt + wr * VSTR + 4 * hp + tg * (TILES_PER_TG * 32);

    for (int ch = 0; ch < NCH; ++ch) {
        __syncthreads();                  // previous chunk's readers done
        // ---- stage TC t-rows (1 per thread): kf wires + padded vt ----
        {
            const int t = ch * TC + tid;
            const float4 xa  = *(const float4*)(xb + t * 8);
            const float4 xb4 = *(const float4*)(xb + t * 8 + 4);
            float c0 = __cosf(xa.x  + th[0]);
            float c1 = __cosf(xa.y  + th[1]);
            float c2 = __cosf(xa.z  + th[2]);
            float c3 = __cosf(xa.w  + th[3]);
            float c4 = __cosf(xb4.x + th[4]);
            float c5 = __cosf(xb4.y + th[5]);
            float c6 = __cosf(xb4.z + th[6]);
            float c7 = __cosf(xb4.w + th[7]);
            float p1 = c0 * c1, p2 = p1 * c2, p3 = p2 * c3, p4 = p3 * c4;
            float p5 = p4 * c5, p6 = p5 * c6, p7 = p6 * c7;
            float p0 = c1 * c2 * c3 * c4 * c5 * c6 * c7;
            _Float16 h0 = (_Float16)p0, h1 = (_Float16)p1, h2 = (_Float16)p2,
                     h3 = (_Float16)p3, h4 = (_Float16)p4, h5 = (_Float16)p5,
                     h6 = (_Float16)p6, h7 = (_Float16)p7;
            _Float16* krow = kf + tid * KSTR;
            *(f16x4*)(krow)     = (f16x4){h0, h1, h2, h3};
            *(f16x4*)(krow + 4) = (f16x4){h4, h5, h6, h7};
            vt[0 * VSTR + tid] = h0;
            vt[1 * VSTR + tid] = h1;
            vt[2 * VSTR + tid] = h2;
            vt[3 * VSTR + tid] = h3;
            vt[4 * VSTR + tid] = h4;
            vt[5 * VSTR + tid] = h5;
            vt[6 * VSTR + tid] = h6;
            vt[7 * VSTR + tid] = h7;
        }
        __syncthreads();
        // ---- 8 t-tiles: QK(K=16) -> exp2/pkrtz -> 2 PV(K=16, permuted k) ----
#pragma unroll 2
        for (int i = 0; i < TILES_PER_TG; ++i) {
            const _Float16* kp = kfb + i * 32 * KSTR;
            union { f16x4 h[2]; f16x8 v; } kfr;
            kfr.h[0] = *(const f16x4*)(kp);
            kfr.h[1] = *(const f16x4*)(kp + 4);
            f32x16 cc = __builtin_amdgcn_mfma_f32_32x32x16_f16(kfr.v, qfrag, Z, 0, 0, 0);
            // P stays in C-reg order; A-frags = C-regs 0..7 and 8..15 verbatim
            union { int i_[4]; f16x8 v; } A0, A1;
#pragma unroll
            for (int j = 0; j < 4; ++j) {
                union { hf2 h; int i_; } t2;
                t2.h = __builtin_amdgcn_cvt_pkrtz(EXP2F(cc[2*j]), EXP2F(cc[2*j+1]));
                A0.i_[j] = t2.i_;
                t2.h = __builtin_amdgcn_cvt_pkrtz(EXP2F(cc[8+2*j]), EXP2F(cc[8+2*j+1]));
                A1.i_[j] = t2.i_;
            }
            // V^T through the same k-scramble: b64s at +0,+8,+16,+24 (+4hp in base)
            const _Float16* vp = vbb + i * 32;
            union { f16x4 h[2]; f16x8 v; } vf0, vf1;
            vf0.h[0] = *(const f16x4*)(vp);
            vf0.h[1] = *(const f16x4*)(vp + 8);
            vf1.h[0] = *(const f16x4*)(vp + 16);
            vf1.h[1] = *(const f16x4*)(vp + 24);
            o = __builtin_amdgcn_mfma_f32_32x32x16_f16(A0.v, vf0.v, o, 0, 0, 0);
            o = __builtin_amdgcn_mfma_f32_32x32x16_f16(A1.v, vf1.v, o, 0, 0, 0);
        }
    }

    // ---- write per-t-group partials (cols 0..8; col 8 = exp-sum) ----
    __syncthreads();                      // all MFMA reads of kf/vt done; alias now
    if (l31 < 9) {
#pragma unroll
        for (int r = 0; r < 16; ++r) {
            const int sloc = sub * 32 + (r & 3) + 8 * (r >> 2) + 4 * hp;
            part[((tg * SROWS) + sloc) * 9 + l31] = o[r];
        }
    }
    __syncthreads();
    // ---- reduce over t-groups (1152 entries > TPB: strided loop!) ----
    for (int idx = tid; idx < SROWS * 9; idx += TPB) {
        const int rr = idx / 9;
        const int w  = idx - rr * 9;
        float sm = 0.f;
#pragma unroll
        for (int g = 0; g < NTG; ++g) sm += part[((g * SROWS) + rr) * 9 + w];
        attn[rr * 9 + w] = sm;
    }
    __syncthreads();
    if (tid < SROWS * 8) {                // normalize in place (col 8 untouched)
        const int rr = tid >> 3;
        const int w  = tid & 7;
        attn[rr * 9 + w] = attn[rr * 9 + w] / attn[rr * 9 + 8];
    }
    __syncthreads();

    // ---- epilogue: swapaxes/reshape scramble + 8x8 combine ----
    if (tid < SROWS) {
        const int e    = tid >> 4;        // wire
        const int nloc = tid & 15;
        const int r    = e * 512 + (S0 >> 3) + nloc;
        float y[8];
#pragma unroll
        for (int c = 0; c < 8; ++c) y[c] = attn[(nloc * 8 + c) * 9 + e];
        float oo[8];
#pragma unroll
        for (int k = 0; k < 8; ++k) {
            float a = bc[k];
#pragma unroll
            for (int c = 0; c < 8; ++c) a += y[c] * wc[k * 8 + c];
            oo[k] = a;
        }
        float4* op = (float4*)(out + ((size_t)b * SEQ + r) * 8);
        op[0] = make_float4(oo[0], oo[1], oo[2], oo[3]);
        op[1] = make_float4(oo[4], oo[5], oo[6], oo[7]);
    }
}

extern "C" void kernel_launch(void* const* d_in, const int* in_sizes, int n_in,
                              void* d_out, int out_size, void* d_ws, size_t ws_size,
                              hipStream_t stream)
{
    const float* x  = (const float*)d_in[0];
    const float* th = (const float*)d_in[1];
    const float* wc = (const float*)d_in[2];
    const float* bc = (const float*)d_in[3];
    float* out = (float*)d_out;

    qattn_kernel<<<dim3(NB * (SEQ / SROWS)), dim3(TPB), 0, stream>>>(x, th, wc, bc, out);
}